// Round 5
// baseline (478.482 us; speedup 1.0000x reference)
//
#include <hip/hip_runtime.h>

#define N_NODES 100000
#define E_EDGES 1600000
// D = HID = 128, H = 4, HD = 32

typedef unsigned short u16;
typedef unsigned int   u32;
typedef float f32x4  __attribute__((ext_vector_type(4)));
typedef short bf16x8 __attribute__((ext_vector_type(8)));

#define SCAN_CHUNK 1024
#define NBLK ((N_NODES + SCAN_CHUNK - 1) / SCAN_CHUNK)   // 98

__device__ __forceinline__ u16 f2b(float f) {
  u32 b = __float_as_uint(f);
  return (u16)((b + 0x7FFFu + ((b >> 16) & 1u)) >> 16);
}
__device__ __forceinline__ float blo(u32 u) { return __uint_as_float(u << 16); }
__device__ __forceinline__ float bhi(u32 u) { return __uint_as_float(u & 0xFFFF0000u); }

// DPP-based add of a permuted lane value (pure VALU — no LDS pipe, no waits).
template<int CTRL>
__device__ __forceinline__ float dpp_add(float d) {
  int x = __builtin_amdgcn_update_dpp(0, __float_as_int(d), CTRL, 0xf, 0xf, true);
  return d + __int_as_float(x);
}
// Reduce across the 16-lane head group (lanes 16h..16h+15):
// xor1, xor2 via quad_perm; cross-quad via half-row mirror; cross-oct via row mirror.
__device__ __forceinline__ float reduce16(float d) {
  d = dpp_add<0xB1>(d);    // quad_perm [1,0,3,2]
  d = dpp_add<0x4E>(d);    // quad_perm [2,3,0,1]
  d = dpp_add<0x141>(d);   // row_half_mirror
  d = dpp_add<0x140>(d);   // row_mirror
  return d;
}

// ---------------------------------------------------------------------------
// setup: zero the CSR count array AND transpose+bf16-convert the weights.
// threads [0, N_NODES)          -> cnt[i] = 0
// threads [N_NODES, N+65536)    -> Wt[mat][n][k] = W[mat][k][n]
// ---------------------------------------------------------------------------
__global__ __launch_bounds__(256) void setup(
    const float* __restrict__ Wq, const float* __restrict__ Wk,
    const float* __restrict__ Wv, const float* __restrict__ Wo,
    u16* __restrict__ Wt, int* __restrict__ cnt)
{
  int tid = blockIdx.x * 256 + threadIdx.x;
  if (tid < N_NODES) {
    cnt[tid] = 0;
  } else {
    int idx = tid - N_NODES;
    if (idx < 65536) {
      int mat = idx >> 14;
      int rem = idx & 16383;
      int n = rem >> 7, k = rem & 127;
      const float* W = (mat == 0) ? Wq : (mat == 1) ? Wk : (mat == 2) ? Wv : Wo;
      Wt[idx] = f2b(W[k * 128 + n]);
    }
  }
}

// ---------------------------------------------------------------------------
// Fused QKV: stage A tile once, loop over Wq/Wk/Wv.
// Q -> Qb[node][128] bf16.
// K,V -> KVi[node][128] u32, interleaved pairs: slot 2c = K elems {2c,2c+1},
//        slot 2c+1 = V elems {2c,2c+1}.
// ---------------------------------------------------------------------------
__global__ __launch_bounds__(256) void gemm_qkv(
    const float* __restrict__ A, const u16* __restrict__ Wt,
    const float* __restrict__ bq, const float* __restrict__ bk,
    const float* __restrict__ bv,
    u16* __restrict__ Qb, u16* __restrict__ KVi16, int M)
{
  __shared__ u16 Alds[64][136];
  __shared__ u16 Blds[128][136];
  const int t = threadIdx.x;
  const int row0 = blockIdx.x * 64;

#pragma unroll
  for (int i = 0; i < 8; ++i) {
    int f = t + i * 256;
    int r = f >> 5, c4 = f & 31;
    int gr = row0 + r; if (gr >= M) gr = M - 1;
    float4 v = ((const float4*)(A + (size_t)gr * 128))[c4];
    u16* dst = &Alds[r][c4 * 4];
    dst[0] = f2b(v.x); dst[1] = f2b(v.y); dst[2] = f2b(v.z); dst[3] = f2b(v.w);
  }

  const int lane = t & 63;
  const int mrow = lane & 15;
  const int q    = lane >> 4;
  const int m0   = (t >> 6) * 16;

  for (int m = 0; m < 3; ++m) {
    __syncthreads();
#pragma unroll
    for (int i = 0; i < 8; ++i) {
      int f = t + i * 256;
      int r = f >> 4, c8 = f & 15;
      uint4 v = ((const uint4*)(Wt + (size_t)m * 16384 + (size_t)r * 128))[c8];
      *(uint4*)&Blds[r][c8 * 8] = v;
    }
    __syncthreads();

    f32x4 acc[8];
#pragma unroll
    for (int c = 0; c < 8; ++c) acc[c] = (f32x4){0.f, 0.f, 0.f, 0.f};
#pragma unroll
    for (int kk = 0; kk < 4; ++kk) {
      const int kb = kk * 32 + q * 8;
      bf16x8 a = *(const bf16x8*)&Alds[m0 + mrow][kb];
#pragma unroll
      for (int c = 0; c < 8; ++c) {
        bf16x8 b = *(const bf16x8*)&Blds[c * 16 + mrow][kb];
        acc[c] = __builtin_amdgcn_mfma_f32_16x16x32_bf16(a, b, acc[c], 0, 0, 0);
      }
    }

    const float* bias = (m == 0) ? bq : (m == 1) ? bk : bv;
#pragma unroll
    for (int c = 0; c < 8; ++c) {
      int gcol = c * 16 + mrow;
      float bvv = bias[gcol];
#pragma unroll
      for (int r = 0; r < 4; ++r) {
        int grow = row0 + m0 + q * 4 + r;
        if (grow < M) {
          u16 val = f2b(acc[c][r] + bvv);
          if (m == 0) {
            Qb[(size_t)grow * 128 + gcol] = val;
          } else {
            int slot = ((gcol >> 1) << 2) + ((m == 1) ? 0 : 2) + (gcol & 1);
            KVi16[(size_t)grow * 256 + slot] = val;
          }
        }
      }
    }
  }
}

// ---------------------------------------------------------------------------
// Final: out(Mx128,f32) = A(bf16, Mx128) @ Wo + bo
// ---------------------------------------------------------------------------
__global__ __launch_bounds__(256) void gemm_out(
    const u16* __restrict__ A, const u16* __restrict__ Wt,
    const float* __restrict__ bias, float* __restrict__ Cout, int M)
{
  __shared__ u16 Alds[64][136];
  __shared__ u16 Blds[128][136];
  const int t = threadIdx.x;
  const int row0 = blockIdx.x * 64;

#pragma unroll
  for (int i = 0; i < 4; ++i) {
    int f = t + i * 256;
    int r = f >> 4, c8 = f & 15;
    int gr = row0 + r; if (gr >= M) gr = M - 1;
    uint4 v = ((const uint4*)(A + (size_t)gr * 128))[c8];
    *(uint4*)&Alds[r][c8 * 8] = v;
  }
#pragma unroll
  for (int i = 0; i < 8; ++i) {
    int f = t + i * 256;
    int r = f >> 4, c8 = f & 15;
    uint4 v = ((const uint4*)(Wt + (size_t)r * 128))[c8];
    *(uint4*)&Blds[r][c8 * 8] = v;
  }
  __syncthreads();

  const int lane = t & 63;
  const int mrow = lane & 15;
  const int q    = lane >> 4;
  const int m0   = (t >> 6) * 16;

  f32x4 acc[8];
#pragma unroll
  for (int c = 0; c < 8; ++c) acc[c] = (f32x4){0.f, 0.f, 0.f, 0.f};
#pragma unroll
  for (int kk = 0; kk < 4; ++kk) {
    const int kb = kk * 32 + q * 8;
    bf16x8 a = *(const bf16x8*)&Alds[m0 + mrow][kb];
#pragma unroll
    for (int c = 0; c < 8; ++c) {
      bf16x8 b = *(const bf16x8*)&Blds[c * 16 + mrow][kb];
      acc[c] = __builtin_amdgcn_mfma_f32_16x16x32_bf16(a, b, acc[c], 0, 0, 0);
    }
  }

#pragma unroll
  for (int c = 0; c < 8; ++c) {
    int gcol = c * 16 + mrow;
    float bv = bias[gcol];
#pragma unroll
    for (int r = 0; r < 4; ++r) {
      int grow = row0 + m0 + q * 4 + r;
      if (grow < M) Cout[(size_t)grow * 128 + gcol] = acc[c][r] + bv;
    }
  }
}

// ---------------------------------------------------------------------------
// CSR build: histogram -> scan_a -> scan_c (with inlined block-sum scan)
// -> cursor scatter (4B packed entries: (src<<15) | ew_q15)
// ---------------------------------------------------------------------------
__global__ __launch_bounds__(256) void count_tgt(const int* __restrict__ ei,
                                                 int* __restrict__ cnt)
{
  int e = blockIdx.x * 256 + threadIdx.x;
  if (e < E_EDGES) atomicAdd(&cnt[ei[E_EDGES + e]], 1);
}

__global__ __launch_bounds__(256) void scan_a(const int* __restrict__ cnt,
                                              int* __restrict__ off,
                                              int* __restrict__ bsum)
{
  __shared__ int s[256];
  int b = blockIdx.x, t = threadIdx.x;
  int base = b * SCAN_CHUNK + t * 4;
  int v0 = (base + 0 < N_NODES) ? cnt[base + 0] : 0;
  int v1 = (base + 1 < N_NODES) ? cnt[base + 1] : 0;
  int v2 = (base + 2 < N_NODES) ? cnt[base + 2] : 0;
  int v3 = (base + 3 < N_NODES) ? cnt[base + 3] : 0;
  int tsum = v0 + v1 + v2 + v3;
  s[t] = tsum;
  __syncthreads();
  for (int d = 1; d < 256; d <<= 1) {
    int x = (t >= d) ? s[t - d] : 0;
    __syncthreads();
    s[t] += x;
    __syncthreads();
  }
  int excl = s[t] - tsum;
  if (t == 255) bsum[b] = s[255];
  if (base + 0 < N_NODES) off[base + 0] = excl; excl += v0;
  if (base + 1 < N_NODES) off[base + 1] = excl; excl += v1;
  if (base + 2 < N_NODES) off[base + 2] = excl; excl += v2;
  if (base + 3 < N_NODES) off[base + 3] = excl;
}

// scan_c with scan_b inlined: every block redundantly scans the 98 block
// sums in LDS (cheap), then adds its exclusive block offset.
__global__ __launch_bounds__(256) void scan_c(int* __restrict__ off,
                                              const int* __restrict__ bsum,
                                              int* __restrict__ cur)
{
  __shared__ int s[256];
  int b = blockIdx.x, t = threadIdx.x;
  int v = (t < NBLK) ? bsum[t] : 0;
  s[t] = v;
  __syncthreads();
  for (int d = 1; d < 128; d <<= 1) {
    int x = (t >= d) ? s[t - d] : 0;
    __syncthreads();
    s[t] += x;
    __syncthreads();
  }
  int add = s[b] - bsum[b];   // exclusive prefix of block b
  int base = b * SCAN_CHUNK + t * 4;
#pragma unroll
  for (int i = 0; i < 4; ++i) {
    int idx = base + i;
    if (idx < N_NODES) {
      int o = off[idx] + add;
      off[idx] = o;
      cur[idx] = o;
    }
  }
  if (b == 0 && t == 0) off[N_NODES] = E_EDGES;
}

__global__ __launch_bounds__(256) void scatter_csr(const int* __restrict__ ei,
                                                   const float* __restrict__ ew,
                                                   int* __restrict__ cur,
                                                   u32* __restrict__ csr)
{
  int e = blockIdx.x * 256 + threadIdx.x;
  if (e >= E_EDGES) return;
  int tgt = ei[E_EDGES + e];
  int pos = atomicAdd(&cur[tgt], 1);
  u32 src = (u32)ei[e];
  u32 ewq = (u32)(ew[e] * 32768.0f);
  csr[pos] = (src << 15) | ewq;
}

// ---------------------------------------------------------------------------
// Fused per-node gather (4-edge unrolled): scores + softmax + aggregation.
// One wave per node; lane j owns elems 2j,2j+1; head = j>>4.
// One uint2 load per edge. Head-dot reduced via DPP (no LDS pipe).
// Writes bf16 result in-place into Qb[node].
// ---------------------------------------------------------------------------
__global__ __launch_bounds__(256) void gather_fused(
    const int* __restrict__ off, const u32* __restrict__ csr,
    u32* __restrict__ Qb32, const u32* __restrict__ KVi,
    const float* __restrict__ We, const float* __restrict__ be)
{
  int node = blockIdx.x * 4 + (threadIdx.x >> 6);
  int j = threadIdx.x & 63;
  int h = j >> 4;

  const float scale = 0.17677669529663687f;   // 1/sqrt(32)
  const float eiq   = 1.0f / 32768.0f;
  u32 qu = Qb32[(size_t)node * 64 + j];
  float q0 = blo(qu) * scale, q1 = bhi(qu) * scale;
  float weq = We[h] * eiq, bE = be[h];

  int i = off[node], s1 = off[node + 1];
  float a0 = 0.f, a1 = 0.f, sum = 0.f;

  for (; i + 4 <= s1; i += 4) {
    u32 c0 = csr[i], c1 = csr[i + 1], c2 = csr[i + 2], c3 = csr[i + 3];
    uint2 kv0 = *(const uint2*)(KVi + (size_t)(c0 >> 15) * 128 + 2 * j);
    uint2 kv1 = *(const uint2*)(KVi + (size_t)(c1 >> 15) * 128 + 2 * j);
    uint2 kv2 = *(const uint2*)(KVi + (size_t)(c2 >> 15) * 128 + 2 * j);
    uint2 kv3 = *(const uint2*)(KVi + (size_t)(c3 >> 15) * 128 + 2 * j);
    float d0 = q0 * blo(kv0.x) + q1 * bhi(kv0.x);
    float d1 = q0 * blo(kv1.x) + q1 * bhi(kv1.x);
    float d2 = q0 * blo(kv2.x) + q1 * bhi(kv2.x);
    float d3 = q0 * blo(kv3.x) + q1 * bhi(kv3.x);
    d0 = reduce16(d0); d1 = reduce16(d1);
    d2 = reduce16(d2); d3 = reduce16(d3);
    float p0 = __expf(d0 + (float)(c0 & 32767u) * weq + bE);
    float p1 = __expf(d1 + (float)(c1 & 32767u) * weq + bE);
    float p2 = __expf(d2 + (float)(c2 & 32767u) * weq + bE);
    float p3 = __expf(d3 + (float)(c3 & 32767u) * weq + bE);
    sum += (p0 + p1) + (p2 + p3);
    a0 += p0 * blo(kv0.y) + p1 * blo(kv1.y);
    a0 += p2 * blo(kv2.y) + p3 * blo(kv3.y);
    a1 += p0 * bhi(kv0.y) + p1 * bhi(kv1.y);
    a1 += p2 * bhi(kv2.y) + p3 * bhi(kv3.y);
  }
  for (; i < s1; ++i) {
    u32 c = csr[i];
    uint2 kv = *(const uint2*)(KVi + (size_t)(c >> 15) * 128 + 2 * j);
    float d = q0 * blo(kv.x) + q1 * bhi(kv.x);
    d = reduce16(d);
    float p = __expf(d + (float)(c & 32767u) * weq + bE);
    sum += p;
    a0 += p * blo(kv.y);
    a1 += p * bhi(kv.y);
  }
  float inv = 1.f / (sum + 1e-8f);
  Qb32[(size_t)node * 64 + j] =
      (u32)f2b(a0 * inv) | ((u32)f2b(a1 * inv) << 16);
}

// ---------------------------------------------------------------------------
extern "C" void kernel_launch(void* const* d_in, const int* in_sizes, int n_in,
                              void* d_out, int out_size, void* d_ws, size_t ws_size,
                              hipStream_t stream) {
  const float* nf = (const float*)d_in[0];
  const int*   ei = (const int*)  d_in[1];
  const float* ew = (const float*)d_in[2];
  const float* Wq = (const float*)d_in[3];
  const float* bq = (const float*)d_in[4];
  const float* Wk = (const float*)d_in[5];
  const float* bk = (const float*)d_in[6];
  const float* Wv = (const float*)d_in[7];
  const float* bv = (const float*)d_in[8];
  const float* Wo = (const float*)d_in[9];
  const float* bo = (const float*)d_in[10];
  const float* We = (const float*)d_in[11];
  const float* be = (const float*)d_in[12];
  float* out = (float*)d_out;

  char* ws = (char*)d_ws;
  u16*  Wt  = (u16*)ws;                                 // 128 KB
  u16*  Qb  = (u16*)(ws + 131072);                      // N*128 bf16 = 25.6 MB
  u16*  KVi16 = Qb + (size_t)N_NODES * 128;             // N*256 u16 = 51.2 MB
  char* p   = (char*)(KVi16 + (size_t)N_NODES * 256);
  u32*  csr = (u32*)p;                  p += (size_t)E_EDGES * 4;   // 6.4 MB
  int*  cnt = (int*)p;                  p += (size_t)N_NODES * 4;
  int*  off = (int*)p;                  p += (size_t)(N_NODES + 1) * 4;
  int*  cur = (int*)p;                  p += (size_t)N_NODES * 4;
  int*  bsum = (int*)p;                 p += 512;

  setup<<<(N_NODES + 65536 + 255) / 256, 256, 0, stream>>>(Wq, Wk, Wv, Wo, Wt, cnt);

  const int mblocks = (N_NODES + 63) / 64;
  gemm_qkv<<<mblocks, 256, 0, stream>>>(nf, Wt, bq, bk, bv, Qb, KVi16, N_NODES);

  count_tgt<<<(E_EDGES + 255) / 256, 256, 0, stream>>>(ei, cnt);
  scan_a<<<NBLK, 256, 0, stream>>>(cnt, off, bsum);
  scan_c<<<NBLK, 256, 0, stream>>>(off, bsum, cur);
  scatter_csr<<<(E_EDGES + 255) / 256, 256, 0, stream>>>(ei, ew, cur, csr);

  gather_fused<<<(N_NODES + 3) / 4, 256, 0, stream>>>(off, csr,
      (u32*)Qb, (const u32*)KVi16, We, be);

  gemm_out<<<mblocks, 256, 0, stream>>>(Qb, Wt + 49152, bo, out, N_NODES);
}

// Round 6
// 466.930 us; speedup vs baseline: 1.0247x; 1.0247x over previous
//
#include <hip/hip_runtime.h>

#define N_NODES 100000
#define E_EDGES 1600000
// D = HID = 128, H = 4, HD = 32

typedef unsigned short u16;
typedef unsigned int   u32;
typedef float f32x4  __attribute__((ext_vector_type(4)));
typedef short bf16x8 __attribute__((ext_vector_type(8)));

#define SCAN_CHUNK 1024
#define NBLK ((N_NODES + SCAN_CHUNK - 1) / SCAN_CHUNK)   // 98

__device__ __forceinline__ u16 f2b(float f) {
  u32 b = __float_as_uint(f);
  return (u16)((b + 0x7FFFu + ((b >> 16) & 1u)) >> 16);
}
__device__ __forceinline__ float blo(u32 u) { return __uint_as_float(u << 16); }
__device__ __forceinline__ float bhi(u32 u) { return __uint_as_float(u & 0xFFFF0000u); }

// DPP-based add of a permuted lane value (pure VALU — no LDS pipe, no waits).
template<int CTRL>
__device__ __forceinline__ float dpp_add(float d) {
  int x = __builtin_amdgcn_update_dpp(0, __float_as_int(d), CTRL, 0xf, 0xf, true);
  return d + __int_as_float(x);
}
// Reduce across an 8-lane group: xor1, xor2 (quad_perm), then half-row mirror.
__device__ __forceinline__ float reduce8(float d) {
  d = dpp_add<0xB1>(d);    // quad_perm [1,0,3,2]
  d = dpp_add<0x4E>(d);    // quad_perm [2,3,0,1]
  d = dpp_add<0x141>(d);   // row_half_mirror (8-lane mirror)
  return d;
}

// ---------------------------------------------------------------------------
// setup: zero the CSR count array AND transpose+bf16-convert the weights.
// ---------------------------------------------------------------------------
__global__ __launch_bounds__(256) void setup(
    const float* __restrict__ Wq, const float* __restrict__ Wk,
    const float* __restrict__ Wv, const float* __restrict__ Wo,
    u16* __restrict__ Wt, int* __restrict__ cnt)
{
  int tid = blockIdx.x * 256 + threadIdx.x;
  if (tid < N_NODES) {
    cnt[tid] = 0;
  } else {
    int idx = tid - N_NODES;
    if (idx < 65536) {
      int mat = idx >> 14;
      int rem = idx & 16383;
      int n = rem >> 7, k = rem & 127;
      const float* W = (mat == 0) ? Wq : (mat == 1) ? Wk : (mat == 2) ? Wv : Wo;
      Wt[idx] = f2b(W[k * 128 + n]);
    }
  }
}

// ---------------------------------------------------------------------------
// Fused QKV: stage A tile once, loop over Wq/Wk/Wv.
// Q -> Qb[node][128] bf16 (row-major).
// K,V -> KVi[node]: 128 u32; elem group g (=c>>2) occupies u16 slots
//        [8g..8g+7] = {K elems 4g..4g+3, V elems 4g..4g+3}. Gather lane
//        g loads one uint4 (u32 slots 4g..4g+3) = K-quad + V-quad.
// ---------------------------------------------------------------------------
__global__ __launch_bounds__(256) void gemm_qkv(
    const float* __restrict__ A, const u16* __restrict__ Wt,
    const float* __restrict__ bq, const float* __restrict__ bk,
    const float* __restrict__ bv,
    u16* __restrict__ Qb, u16* __restrict__ KVi16, int M)
{
  __shared__ u16 Alds[64][136];
  __shared__ u16 Blds[128][136];
  const int t = threadIdx.x;
  const int row0 = blockIdx.x * 64;

#pragma unroll
  for (int i = 0; i < 8; ++i) {
    int f = t + i * 256;
    int r = f >> 5, c4 = f & 31;
    int gr = row0 + r; if (gr >= M) gr = M - 1;
    float4 v = ((const float4*)(A + (size_t)gr * 128))[c4];
    u16* dst = &Alds[r][c4 * 4];
    dst[0] = f2b(v.x); dst[1] = f2b(v.y); dst[2] = f2b(v.z); dst[3] = f2b(v.w);
  }

  const int lane = t & 63;
  const int mrow = lane & 15;
  const int q    = lane >> 4;
  const int m0   = (t >> 6) * 16;

  for (int m = 0; m < 3; ++m) {
    __syncthreads();
#pragma unroll
    for (int i = 0; i < 8; ++i) {
      int f = t + i * 256;
      int r = f >> 4, c8 = f & 15;
      uint4 v = ((const uint4*)(Wt + (size_t)m * 16384 + (size_t)r * 128))[c8];
      *(uint4*)&Blds[r][c8 * 8] = v;
    }
    __syncthreads();

    f32x4 acc[8];
#pragma unroll
    for (int c = 0; c < 8; ++c) acc[c] = (f32x4){0.f, 0.f, 0.f, 0.f};
#pragma unroll
    for (int kk = 0; kk < 4; ++kk) {
      const int kb = kk * 32 + q * 8;
      bf16x8 a = *(const bf16x8*)&Alds[m0 + mrow][kb];
#pragma unroll
      for (int c = 0; c < 8; ++c) {
        bf16x8 b = *(const bf16x8*)&Blds[c * 16 + mrow][kb];
        acc[c] = __builtin_amdgcn_mfma_f32_16x16x32_bf16(a, b, acc[c], 0, 0, 0);
      }
    }

    const float* bias = (m == 0) ? bq : (m == 1) ? bk : bv;
#pragma unroll
    for (int c = 0; c < 8; ++c) {
      int gcol = c * 16 + mrow;
      float bvv = bias[gcol];
#pragma unroll
      for (int r = 0; r < 4; ++r) {
        int grow = row0 + m0 + q * 4 + r;
        if (grow < M) {
          u16 val = f2b(acc[c][r] + bvv);
          if (m == 0) {
            Qb[(size_t)grow * 128 + gcol] = val;
          } else {
            int slot = ((gcol >> 2) << 3) + ((m == 2) ? 4 : 0) + (gcol & 3);
            KVi16[(size_t)grow * 256 + slot] = val;
          }
        }
      }
    }
  }
}

// ---------------------------------------------------------------------------
// Final: out(Mx128,f32) = A(bf16, Mx128) @ Wo + bo
// ---------------------------------------------------------------------------
__global__ __launch_bounds__(256) void gemm_out(
    const u16* __restrict__ A, const u16* __restrict__ Wt,
    const float* __restrict__ bias, float* __restrict__ Cout, int M)
{
  __shared__ u16 Alds[64][136];
  __shared__ u16 Blds[128][136];
  const int t = threadIdx.x;
  const int row0 = blockIdx.x * 64;

#pragma unroll
  for (int i = 0; i < 4; ++i) {
    int f = t + i * 256;
    int r = f >> 4, c8 = f & 15;
    int gr = row0 + r; if (gr >= M) gr = M - 1;
    uint4 v = ((const uint4*)(A + (size_t)gr * 128))[c8];
    *(uint4*)&Alds[r][c8 * 8] = v;
  }
#pragma unroll
  for (int i = 0; i < 8; ++i) {
    int f = t + i * 256;
    int r = f >> 4, c8 = f & 15;
    uint4 v = ((const uint4*)(Wt + (size_t)r * 128))[c8];
    *(uint4*)&Blds[r][c8 * 8] = v;
  }
  __syncthreads();

  const int lane = t & 63;
  const int mrow = lane & 15;
  const int q    = lane >> 4;
  const int m0   = (t >> 6) * 16;

  f32x4 acc[8];
#pragma unroll
  for (int c = 0; c < 8; ++c) acc[c] = (f32x4){0.f, 0.f, 0.f, 0.f};
#pragma unroll
  for (int kk = 0; kk < 4; ++kk) {
    const int kb = kk * 32 + q * 8;
    bf16x8 a = *(const bf16x8*)&Alds[m0 + mrow][kb];
#pragma unroll
    for (int c = 0; c < 8; ++c) {
      bf16x8 b = *(const bf16x8*)&Blds[c * 16 + mrow][kb];
      acc[c] = __builtin_amdgcn_mfma_f32_16x16x32_bf16(a, b, acc[c], 0, 0, 0);
    }
  }

#pragma unroll
  for (int c = 0; c < 8; ++c) {
    int gcol = c * 16 + mrow;
    float bv = bias[gcol];
#pragma unroll
    for (int r = 0; r < 4; ++r) {
      int grow = row0 + m0 + q * 4 + r;
      if (grow < M) Cout[(size_t)grow * 128 + gcol] = acc[c][r] + bv;
    }
  }
}

// ---------------------------------------------------------------------------
// CSR build: histogram -> scan_a -> scan_c -> cursor scatter (4B entries)
// ---------------------------------------------------------------------------
__global__ __launch_bounds__(256) void count_tgt(const int* __restrict__ ei,
                                                 int* __restrict__ cnt)
{
  int e = blockIdx.x * 256 + threadIdx.x;
  if (e < E_EDGES) atomicAdd(&cnt[ei[E_EDGES + e]], 1);
}

__global__ __launch_bounds__(256) void scan_a(const int* __restrict__ cnt,
                                              int* __restrict__ off,
                                              int* __restrict__ bsum)
{
  __shared__ int s[256];
  int b = blockIdx.x, t = threadIdx.x;
  int base = b * SCAN_CHUNK + t * 4;
  int v0 = (base + 0 < N_NODES) ? cnt[base + 0] : 0;
  int v1 = (base + 1 < N_NODES) ? cnt[base + 1] : 0;
  int v2 = (base + 2 < N_NODES) ? cnt[base + 2] : 0;
  int v3 = (base + 3 < N_NODES) ? cnt[base + 3] : 0;
  int tsum = v0 + v1 + v2 + v3;
  s[t] = tsum;
  __syncthreads();
  for (int d = 1; d < 256; d <<= 1) {
    int x = (t >= d) ? s[t - d] : 0;
    __syncthreads();
    s[t] += x;
    __syncthreads();
  }
  int excl = s[t] - tsum;
  if (t == 255) bsum[b] = s[255];
  if (base + 0 < N_NODES) off[base + 0] = excl; excl += v0;
  if (base + 1 < N_NODES) off[base + 1] = excl; excl += v1;
  if (base + 2 < N_NODES) off[base + 2] = excl; excl += v2;
  if (base + 3 < N_NODES) off[base + 3] = excl;
}

__global__ __launch_bounds__(256) void scan_c(int* __restrict__ off,
                                              const int* __restrict__ bsum,
                                              int* __restrict__ cur)
{
  __shared__ int s[256];
  int b = blockIdx.x, t = threadIdx.x;
  int v = (t < NBLK) ? bsum[t] : 0;
  s[t] = v;
  __syncthreads();
  for (int d = 1; d < 128; d <<= 1) {
    int x = (t >= d) ? s[t - d] : 0;
    __syncthreads();
    s[t] += x;
    __syncthreads();
  }
  int add = s[b] - bsum[b];   // exclusive prefix of block b
  int base = b * SCAN_CHUNK + t * 4;
#pragma unroll
  for (int i = 0; i < 4; ++i) {
    int idx = base + i;
    if (idx < N_NODES) {
      int o = off[idx] + add;
      off[idx] = o;
      cur[idx] = o;
    }
  }
  if (b == 0 && t == 0) off[N_NODES] = E_EDGES;
}

__global__ __launch_bounds__(256) void scatter_csr(const int* __restrict__ ei,
                                                   const float* __restrict__ ew,
                                                   int* __restrict__ cur,
                                                   u32* __restrict__ csr)
{
  int e = blockIdx.x * 256 + threadIdx.x;
  if (e >= E_EDGES) return;
  int tgt = ei[E_EDGES + e];
  int pos = atomicAdd(&cur[tgt], 1);
  u32 src = (u32)ei[e];
  u32 ewq = (u32)(ew[e] * 32768.0f);
  csr[pos] = (src << 15) | ewq;
}

// ---------------------------------------------------------------------------
// Fused per-node gather, 2 edges per wave:
//   lanes 0-31 process even edges, 32-63 odd edges of the node's segment.
//   Within a half: 8 lanes per head, lane owns 4 elems; one uint4 load =
//   K-quad + V-quad. Head dot reduced over 8 lanes (3 DPP rounds).
//   Halves combined once at the end via shfl_xor(32).
// Writes bf16 result in-place into Qb[node].
// ---------------------------------------------------------------------------
__global__ __launch_bounds__(256) void gather_fused(
    const int* __restrict__ off, const u32* __restrict__ csr,
    u32* __restrict__ Qb32, const u32* __restrict__ KVi,
    const float* __restrict__ We, const float* __restrict__ be)
{
  int node = blockIdx.x * 4 + (threadIdx.x >> 6);
  int l    = threadIdx.x & 63;
  int half = l >> 5;            // 0 = even edges, 1 = odd edges
  int hl   = l & 31;            // group index g: elems 4g..4g+3, head g>>3
  int h    = hl >> 3;

  const float scale = 0.17677669529663687f;   // 1/sqrt(32)
  const float eiq   = 1.0f / 32768.0f;
  uint2 qp = *(const uint2*)(Qb32 + (size_t)node * 64 + hl * 2);
  float qa = blo(qp.x) * scale, qb = bhi(qp.x) * scale;
  float qc = blo(qp.y) * scale, qd = bhi(qp.y) * scale;
  float weq = We[h] * eiq, bE = be[h];
  const u32 laneKV = (u32)hl * 16;   // byte offset of this lane's uint4

  int s0 = off[node];
  int L  = off[node + 1] - s0;
  int npair = L >> 1;
  const u32* cp = csr + s0 + half;   // this half's edge stream (stride 2)
  const char* KVc = (const char*)KVi;

  float a0 = 0.f, a1 = 0.f, a2 = 0.f, a3 = 0.f, sum = 0.f;

  int i = 0;
  for (; i + 2 <= npair; i += 2) {
    u32 ca = cp[2 * i];
    u32 cb = cp[2 * i + 2];
    uint4 kva = *(const uint4*)(KVc + (((ca >> 15) << 9) + laneKV));
    uint4 kvb = *(const uint4*)(KVc + (((cb >> 15) << 9) + laneKV));
    float da = qa * blo(kva.x) + qb * bhi(kva.x) + qc * blo(kva.y) + qd * bhi(kva.y);
    float db = qa * blo(kvb.x) + qb * bhi(kvb.x) + qc * blo(kvb.y) + qd * bhi(kvb.y);
    da = reduce8(da);
    db = reduce8(db);
    float pa = __expf(da + (float)(ca & 32767u) * weq + bE);
    float pb = __expf(db + (float)(cb & 32767u) * weq + bE);
    sum += pa + pb;
    a0 += pa * blo(kva.z) + pb * blo(kvb.z);
    a1 += pa * bhi(kva.z) + pb * bhi(kvb.z);
    a2 += pa * blo(kva.w) + pb * blo(kvb.w);
    a3 += pa * bhi(kva.w) + pb * bhi(kvb.w);
  }
  if (i < npair) {
    u32 c = cp[2 * i];
    uint4 kv = *(const uint4*)(KVc + (((c >> 15) << 9) + laneKV));
    float d = qa * blo(kv.x) + qb * bhi(kv.x) + qc * blo(kv.y) + qd * bhi(kv.y);
    d = reduce8(d);
    float p = __expf(d + (float)(c & 32767u) * weq + bE);
    sum += p;
    a0 += p * blo(kv.z);
    a1 += p * bhi(kv.z);
    a2 += p * blo(kv.w);
    a3 += p * bhi(kv.w);
  }
  if (L & 1) {   // tail edge: both halves compute it; zero p in upper half
    u32 c = csr[s0 + L - 1];
    uint4 kv = *(const uint4*)(KVc + (((c >> 15) << 9) + laneKV));
    float d = qa * blo(kv.x) + qb * bhi(kv.x) + qc * blo(kv.y) + qd * bhi(kv.y);
    d = reduce8(d);
    float p = __expf(d + (float)(c & 32767u) * weq + bE);
    p = half ? 0.f : p;
    sum += p;
    a0 += p * blo(kv.z);
    a1 += p * bhi(kv.z);
    a2 += p * blo(kv.w);
    a3 += p * bhi(kv.w);
  }

  // combine the two halves (after this, both halves hold identical values)
  sum += __shfl_xor(sum, 32, 64);
  a0  += __shfl_xor(a0, 32, 64);
  a1  += __shfl_xor(a1, 32, 64);
  a2  += __shfl_xor(a2, 32, 64);
  a3  += __shfl_xor(a3, 32, 64);

  float inv = 1.f / (sum + 1e-8f);
  if (half == 0) {
    uint2 w;
    w.x = (u32)f2b(a0 * inv) | ((u32)f2b(a1 * inv) << 16);
    w.y = (u32)f2b(a2 * inv) | ((u32)f2b(a3 * inv) << 16);
    *(uint2*)(Qb32 + (size_t)node * 64 + hl * 2) = w;
  }
}

// ---------------------------------------------------------------------------
extern "C" void kernel_launch(void* const* d_in, const int* in_sizes, int n_in,
                              void* d_out, int out_size, void* d_ws, size_t ws_size,
                              hipStream_t stream) {
  const float* nf = (const float*)d_in[0];
  const int*   ei = (const int*)  d_in[1];
  const float* ew = (const float*)d_in[2];
  const float* Wq = (const float*)d_in[3];
  const float* bq = (const float*)d_in[4];
  const float* Wk = (const float*)d_in[5];
  const float* bk = (const float*)d_in[6];
  const float* Wv = (const float*)d_in[7];
  const float* bv = (const float*)d_in[8];
  const float* Wo = (const float*)d_in[9];
  const float* bo = (const float*)d_in[10];
  const float* We = (const float*)d_in[11];
  const float* be = (const float*)d_in[12];
  float* out = (float*)d_out;

  char* ws = (char*)d_ws;
  u16*  Wt  = (u16*)ws;                                 // 128 KB
  u16*  Qb  = (u16*)(ws + 131072);                      // N*128 bf16 = 25.6 MB
  u16*  KVi16 = Qb + (size_t)N_NODES * 128;             // N*256 u16 = 51.2 MB
  char* p   = (char*)(KVi16 + (size_t)N_NODES * 256);
  u32*  csr = (u32*)p;                  p += (size_t)E_EDGES * 4;   // 6.4 MB
  int*  cnt = (int*)p;                  p += (size_t)N_NODES * 4;
  int*  off = (int*)p;                  p += (size_t)(N_NODES + 1) * 4;
  int*  cur = (int*)p;                  p += (size_t)N_NODES * 4;
  int*  bsum = (int*)p;                 p += 512;

  setup<<<(N_NODES + 65536 + 255) / 256, 256, 0, stream>>>(Wq, Wk, Wv, Wo, Wt, cnt);

  const int mblocks = (N_NODES + 63) / 64;
  gemm_qkv<<<mblocks, 256, 0, stream>>>(nf, Wt, bq, bk, bv, Qb, KVi16, N_NODES);

  count_tgt<<<(E_EDGES + 255) / 256, 256, 0, stream>>>(ei, cnt);
  scan_a<<<NBLK, 256, 0, stream>>>(cnt, off, bsum);
  scan_c<<<NBLK, 256, 0, stream>>>(off, bsum, cur);
  scatter_csr<<<(E_EDGES + 255) / 256, 256, 0, stream>>>(ei, ew, cur, csr);

  gather_fused<<<(N_NODES + 3) / 4, 256, 0, stream>>>(off, csr,
      (u32*)Qb, (const u32*)KVi16, We, be);

  gemm_out<<<mblocks, 256, 0, stream>>>(Qb, Wt + 49152, bo, out, N_NODES);
}

// Round 7
// 377.764 us; speedup vs baseline: 1.2666x; 1.2360x over previous
//
#include <hip/hip_runtime.h>

#define N_NODES 100000
#define E_EDGES 1600000
// D = HID = 128, H = 4, HD = 32

typedef unsigned short u16;
typedef unsigned int   u32;
typedef float f32x4  __attribute__((ext_vector_type(4)));
typedef short bf16x8 __attribute__((ext_vector_type(8)));

#define NBUK 98            // buckets of 1024 nodes: bucket = tgt >> 10

__device__ __forceinline__ u16 f2b(float f) {
  u32 b = __float_as_uint(f);
  return (u16)((b + 0x7FFFu + ((b >> 16) & 1u)) >> 16);
}
__device__ __forceinline__ float blo(u32 u) { return __uint_as_float(u << 16); }
__device__ __forceinline__ float bhi(u32 u) { return __uint_as_float(u & 0xFFFF0000u); }

template<int CTRL>
__device__ __forceinline__ float dpp_add(float d) {
  int x = __builtin_amdgcn_update_dpp(0, __float_as_int(d), CTRL, 0xf, 0xf, true);
  return d + __int_as_float(x);
}
// Reduce across an 8-lane group: xor1, xor2 (quad_perm), then half-row mirror.
__device__ __forceinline__ float reduce8(float d) {
  d = dpp_add<0xB1>(d);    // quad_perm [1,0,3,2]
  d = dpp_add<0x4E>(d);    // quad_perm [2,3,0,1]
  d = dpp_add<0x141>(d);   // row_half_mirror
  return d;
}

// ---------------------------------------------------------------------------
// setup: zero the 98 bucket counters AND transpose+bf16-convert the weights.
// ---------------------------------------------------------------------------
__global__ __launch_bounds__(256) void setup(
    const float* __restrict__ Wq, const float* __restrict__ Wk,
    const float* __restrict__ Wv, const float* __restrict__ Wo,
    u16* __restrict__ Wt, u32* __restrict__ bcnt)
{
  int tid = blockIdx.x * 256 + threadIdx.x;
  if (tid < NBUK) bcnt[tid] = 0;
  int idx = tid - NBUK;
  if (idx >= 0 && idx < 65536) {
    int mat = idx >> 14;
    int rem = idx & 16383;
    int n = rem >> 7, k = rem & 127;
    const float* W = (mat == 0) ? Wq : (mat == 1) ? Wk : (mat == 2) ? Wv : Wo;
    Wt[idx] = f2b(W[k * 128 + n]);
  }
}

// ---------------------------------------------------------------------------
// Fused QKV: stage A tile once, loop over Wq/Wk/Wv.
// Q -> Qb[node][128] bf16.  K,V -> KVi[node]: elem group g = c>>2 occupies
// u16 slots [8g..8g+7] = {K elems 4g..4g+3, V elems 4g..4g+3}.
// ---------------------------------------------------------------------------
__global__ __launch_bounds__(256) void gemm_qkv(
    const float* __restrict__ A, const u16* __restrict__ Wt,
    const float* __restrict__ bq, const float* __restrict__ bk,
    const float* __restrict__ bv,
    u16* __restrict__ Qb, u16* __restrict__ KVi16, int M)
{
  __shared__ u16 Alds[64][136];
  __shared__ u16 Blds[128][136];
  const int t = threadIdx.x;
  const int row0 = blockIdx.x * 64;

#pragma unroll
  for (int i = 0; i < 8; ++i) {
    int f = t + i * 256;
    int r = f >> 5, c4 = f & 31;
    int gr = row0 + r; if (gr >= M) gr = M - 1;
    float4 v = ((const float4*)(A + (size_t)gr * 128))[c4];
    u16* dst = &Alds[r][c4 * 4];
    dst[0] = f2b(v.x); dst[1] = f2b(v.y); dst[2] = f2b(v.z); dst[3] = f2b(v.w);
  }

  const int lane = t & 63;
  const int mrow = lane & 15;
  const int q    = lane >> 4;
  const int m0   = (t >> 6) * 16;

  for (int m = 0; m < 3; ++m) {
    __syncthreads();
#pragma unroll
    for (int i = 0; i < 8; ++i) {
      int f = t + i * 256;
      int r = f >> 4, c8 = f & 15;
      uint4 v = ((const uint4*)(Wt + (size_t)m * 16384 + (size_t)r * 128))[c8];
      *(uint4*)&Blds[r][c8 * 8] = v;
    }
    __syncthreads();

    f32x4 acc[8];
#pragma unroll
    for (int c = 0; c < 8; ++c) acc[c] = (f32x4){0.f, 0.f, 0.f, 0.f};
#pragma unroll
    for (int kk = 0; kk < 4; ++kk) {
      const int kb = kk * 32 + q * 8;
      bf16x8 a = *(const bf16x8*)&Alds[m0 + mrow][kb];
#pragma unroll
      for (int c = 0; c < 8; ++c) {
        bf16x8 b = *(const bf16x8*)&Blds[c * 16 + mrow][kb];
        acc[c] = __builtin_amdgcn_mfma_f32_16x16x32_bf16(a, b, acc[c], 0, 0, 0);
      }
    }

    const float* bias = (m == 0) ? bq : (m == 1) ? bk : bv;
#pragma unroll
    for (int c = 0; c < 8; ++c) {
      int gcol = c * 16 + mrow;
      float bvv = bias[gcol];
#pragma unroll
      for (int r = 0; r < 4; ++r) {
        int grow = row0 + m0 + q * 4 + r;
        if (grow < M) {
          u16 val = f2b(acc[c][r] + bvv);
          if (m == 0) {
            Qb[(size_t)grow * 128 + gcol] = val;
          } else {
            int slot = ((gcol >> 2) << 3) + ((m == 2) ? 4 : 0) + (gcol & 3);
            KVi16[(size_t)grow * 256 + slot] = val;
          }
        }
      }
    }
  }
}

// ---------------------------------------------------------------------------
// Final: out(Mx128,f32) = A(bf16, Mx128) @ Wo + bo
// ---------------------------------------------------------------------------
__global__ __launch_bounds__(256) void gemm_out(
    const u16* __restrict__ A, const u16* __restrict__ Wt,
    const float* __restrict__ bias, float* __restrict__ Cout, int M)
{
  __shared__ u16 Alds[64][136];
  __shared__ u16 Blds[128][136];
  const int t = threadIdx.x;
  const int row0 = blockIdx.x * 64;

#pragma unroll
  for (int i = 0; i < 4; ++i) {
    int f = t + i * 256;
    int r = f >> 4, c8 = f & 15;
    int gr = row0 + r; if (gr >= M) gr = M - 1;
    uint4 v = ((const uint4*)(A + (size_t)gr * 128))[c8];
    *(uint4*)&Alds[r][c8 * 8] = v;
  }
#pragma unroll
  for (int i = 0; i < 8; ++i) {
    int f = t + i * 256;
    int r = f >> 4, c8 = f & 15;
    uint4 v = ((const uint4*)(Wt + (size_t)r * 128))[c8];
    *(uint4*)&Blds[r][c8 * 8] = v;
  }
  __syncthreads();

  const int lane = t & 63;
  const int mrow = lane & 15;
  const int q    = lane >> 4;
  const int m0   = (t >> 6) * 16;

  f32x4 acc[8];
#pragma unroll
  for (int c = 0; c < 8; ++c) acc[c] = (f32x4){0.f, 0.f, 0.f, 0.f};
#pragma unroll
  for (int kk = 0; kk < 4; ++kk) {
    const int kb = kk * 32 + q * 8;
    bf16x8 a = *(const bf16x8*)&Alds[m0 + mrow][kb];
#pragma unroll
    for (int c = 0; c < 8; ++c) {
      bf16x8 b = *(const bf16x8*)&Blds[c * 16 + mrow][kb];
      acc[c] = __builtin_amdgcn_mfma_f32_16x16x32_bf16(a, b, acc[c], 0, 0, 0);
    }
  }

#pragma unroll
  for (int c = 0; c < 8; ++c) {
    int gcol = c * 16 + mrow;
    float bv = bias[gcol];
#pragma unroll
    for (int r = 0; r < 4; ++r) {
      int grow = row0 + m0 + q * 4 + r;
      if (grow < M) Cout[(size_t)grow * 128 + gcol] = acc[c][r] + bv;
    }
  }
}

// ---------------------------------------------------------------------------
// Bucket histogram: per-block LDS hist of tgt>>10, 98 global atomics/block.
// ---------------------------------------------------------------------------
__global__ __launch_bounds__(256) void bucket_count(
    const int* __restrict__ ei, u32* __restrict__ bcnt)
{
  __shared__ u32 s_h[NBUK];
  const int t = threadIdx.x;
  if (t < NBUK) s_h[t] = 0;
  __syncthreads();
  const int base = blockIdx.x * 4096;
  const int nv = min(4096, E_EDGES - base);
  for (int i = t; i < nv; i += 256) {
    u32 tg = (u32)ei[E_EDGES + base + i];
    atomicAdd(&s_h[tg >> 10], 1u);
  }
  __syncthreads();
  if (t < NBUK && s_h[t]) atomicAdd(&bcnt[t], s_h[t]);
}

// ---------------------------------------------------------------------------
// Scan the 98 bucket counts -> bbase[0..98], init bcur.
// ---------------------------------------------------------------------------
__global__ __launch_bounds__(128) void bucket_scan(
    const u32* __restrict__ bcnt, u32* __restrict__ bbase, u32* __restrict__ bcur)
{
  __shared__ int s[128];
  int t = threadIdx.x;
  int v = (t < NBUK) ? (int)bcnt[t] : 0;
  s[t] = v;
  __syncthreads();
  for (int d = 1; d < 128; d <<= 1) {
    int x = (t >= d) ? s[t - d] : 0;
    __syncthreads();
    s[t] += x;
    __syncthreads();
  }
  if (t < NBUK) { bbase[t] = s[t] - v; bcur[t] = s[t] - v; }
  if (t == 0) bbase[NBUK] = E_EDGES;
}

// ---------------------------------------------------------------------------
// pass1: bin 4096 edges/block by bucket via LDS counting sort; claim one
// contiguous run per bucket (single atomicAdd) and write staged (tgt,payload)
// pairs in coalesced runs.  payload = (src<<15) | ew_q15.
// ---------------------------------------------------------------------------
__global__ __launch_bounds__(256) void pass1_bin(
    const int* __restrict__ ei, const float* __restrict__ ew,
    u32* __restrict__ bcur, uint2* __restrict__ stag)
{
  __shared__ u32 s_px[4096];
  __shared__ u32 s_py[4096];
  __shared__ u32 s_gp[4096];
  __shared__ u32 s_hist[NBUK];
  __shared__ u32 s_excl[NBUK];
  __shared__ u32 s_gbase[NBUK];
  __shared__ int s_scan[128];
  const int t = threadIdx.x;
  const int base = blockIdx.x * 4096;
  const int nv = min(4096, E_EDGES - base);

  if (t < NBUK) s_hist[t] = 0;
  __syncthreads();

  u32 tg[16], py[16];
#pragma unroll
  for (int i = 0; i < 16; ++i) {
    int li = t + i * 256;
    bool valid = li < nv;
    int e = base + (valid ? li : 0);
    tg[i] = (u32)ei[E_EDGES + e];
    u32 src = (u32)ei[e];
    u32 ewq = (u32)(ew[e] * 32768.0f);
    py[i] = (src << 15) | ewq;
    if (valid) atomicAdd(&s_hist[tg[i] >> 10], 1u);
    else tg[i] = 0xFFFFFFFFu;
  }
  __syncthreads();

  // scan 98 counts (128-lane ladder; all 256 threads hit the syncs)
  {
    int v = (t < NBUK) ? (int)s_hist[t] : 0;
    if (t < 128) s_scan[t] = v;
    __syncthreads();
    for (int d = 1; d < 128; d <<= 1) {
      int x = (t >= d && t < 128) ? s_scan[t - d] : 0;
      __syncthreads();
      if (t < 128) s_scan[t] += x;
      __syncthreads();
    }
    if (t < NBUK) {
      s_excl[t] = (u32)(s_scan[t] - v);
      s_gbase[t] = (v > 0) ? atomicAdd(&bcur[t], (u32)v) : 0u;
    }
  }
  __syncthreads();
  if (t < NBUK) s_hist[t] = s_excl[t];   // reuse as LDS cursor
  __syncthreads();

#pragma unroll
  for (int i = 0; i < 16; ++i) {
    if (tg[i] != 0xFFFFFFFFu) {
      u32 bk = tg[i] >> 10;
      u32 lp = atomicAdd(&s_hist[bk], 1u);
      s_px[lp] = tg[i];
      s_py[lp] = py[i];
      s_gp[lp] = s_gbase[bk] + (lp - s_excl[bk]);
    }
  }
  __syncthreads();
  for (int s = t; s < nv; s += 256)
    stag[s_gp[s]] = make_uint2(s_px[s], s_py[s]);
}

// ---------------------------------------------------------------------------
// pass2: one block per bucket. LDS per-node histogram + scan -> off[]; then
// scatter staged entries via LDS cursors into the bucket's csr window
// (random writes confined to ~65 KB -> L2-resident).
// ---------------------------------------------------------------------------
__global__ __launch_bounds__(1024) void pass2_scatter(
    const u32* __restrict__ bbase, const uint2* __restrict__ stag,
    int* __restrict__ off, u32* __restrict__ csr)
{
  __shared__ int s_hist[1024];
  __shared__ int s_scan[1024];
  const int t = threadIdx.x;
  const int b = blockIdx.x;
  const int sb = (int)bbase[b], se = (int)bbase[b + 1];
  const int cnt = se - sb;
  const int node_base = b << 10;

  s_hist[t] = 0;
  __syncthreads();
  for (int i = t; i < cnt; i += 1024)
    atomicAdd(&s_hist[stag[sb + i].x & 1023], 1);
  __syncthreads();

  int v = s_hist[t];
  s_scan[t] = v;
  __syncthreads();
  for (int d = 1; d < 1024; d <<= 1) {
    int x = (t >= d) ? s_scan[t - d] : 0;
    __syncthreads();
    s_scan[t] += x;
    __syncthreads();
  }
  int excl = s_scan[t] - v;
  int node = node_base + t;
  if (node <= N_NODES) off[node] = sb + excl;   // node==N gets sb+cnt==E in last bucket
  __syncthreads();
  s_hist[t] = sb + excl;   // absolute cursor
  __syncthreads();
  for (int i = t; i < cnt; i += 1024) {
    uint2 pr = stag[sb + i];
    int pos = atomicAdd(&s_hist[pr.x & 1023], 1);
    csr[pos] = pr.y;
  }
}

// ---------------------------------------------------------------------------
// Fused per-node gather, 2 edges per wave (lanes 0-31 even edges, 32-63 odd).
// Within a half: 8 lanes/head, lane owns 4 elems; one uint4 = K-quad+V-quad.
// ---------------------------------------------------------------------------
__global__ __launch_bounds__(256) void gather_fused(
    const int* __restrict__ off, const u32* __restrict__ csr,
    u32* __restrict__ Qb32, const u32* __restrict__ KVi,
    const float* __restrict__ We, const float* __restrict__ be)
{
  int node = blockIdx.x * 4 + (threadIdx.x >> 6);
  int l    = threadIdx.x & 63;
  int half = l >> 5;
  int hl   = l & 31;
  int h    = hl >> 3;

  const float scale = 0.17677669529663687f;   // 1/sqrt(32)
  const float eiq   = 1.0f / 32768.0f;
  uint2 qp = *(const uint2*)(Qb32 + (size_t)node * 64 + hl * 2);
  float qa = blo(qp.x) * scale, qb = bhi(qp.x) * scale;
  float qc = blo(qp.y) * scale, qd = bhi(qp.y) * scale;
  float weq = We[h] * eiq, bE = be[h];
  const u32 laneKV = (u32)hl * 16;

  int s0 = off[node];
  int L  = off[node + 1] - s0;
  int npair = L >> 1;
  const u32* cp = csr + s0 + half;
  const char* KVc = (const char*)KVi;

  float a0 = 0.f, a1 = 0.f, a2 = 0.f, a3 = 0.f, sum = 0.f;

  int i = 0;
  for (; i + 2 <= npair; i += 2) {
    u32 ca = cp[2 * i];
    u32 cb = cp[2 * i + 2];
    uint4 kva = *(const uint4*)(KVc + (((ca >> 15) << 9) + laneKV));
    uint4 kvb = *(const uint4*)(KVc + (((cb >> 15) << 9) + laneKV));
    float da = qa * blo(kva.x) + qb * bhi(kva.x) + qc * blo(kva.y) + qd * bhi(kva.y);
    float db = qa * blo(kvb.x) + qb * bhi(kvb.x) + qc * blo(kvb.y) + qd * bhi(kvb.y);
    da = reduce8(da);
    db = reduce8(db);
    float pa = __expf(da + (float)(ca & 32767u) * weq + bE);
    float pb = __expf(db + (float)(cb & 32767u) * weq + bE);
    sum += pa + pb;
    a0 += pa * blo(kva.z) + pb * blo(kvb.z);
    a1 += pa * bhi(kva.z) + pb * bhi(kvb.z);
    a2 += pa * blo(kva.w) + pb * blo(kvb.w);
    a3 += pa * bhi(kva.w) + pb * bhi(kvb.w);
  }
  if (i < npair) {
    u32 c = cp[2 * i];
    uint4 kv = *(const uint4*)(KVc + (((c >> 15) << 9) + laneKV));
    float d = qa * blo(kv.x) + qb * bhi(kv.x) + qc * blo(kv.y) + qd * bhi(kv.y);
    d = reduce8(d);
    float p = __expf(d + (float)(c & 32767u) * weq + bE);
    sum += p;
    a0 += p * blo(kv.z);
    a1 += p * bhi(kv.z);
    a2 += p * blo(kv.w);
    a3 += p * bhi(kv.w);
  }
  if (L & 1) {
    u32 c = csr[s0 + L - 1];
    uint4 kv = *(const uint4*)(KVc + (((c >> 15) << 9) + laneKV));
    float d = qa * blo(kv.x) + qb * bhi(kv.x) + qc * blo(kv.y) + qd * bhi(kv.y);
    d = reduce8(d);
    float p = __expf(d + (float)(c & 32767u) * weq + bE);
    p = half ? 0.f : p;
    sum += p;
    a0 += p * blo(kv.z);
    a1 += p * bhi(kv.z);
    a2 += p * blo(kv.w);
    a3 += p * bhi(kv.w);
  }

  sum += __shfl_xor(sum, 32, 64);
  a0  += __shfl_xor(a0, 32, 64);
  a1  += __shfl_xor(a1, 32, 64);
  a2  += __shfl_xor(a2, 32, 64);
  a3  += __shfl_xor(a3, 32, 64);

  float inv = 1.f / (sum + 1e-8f);
  if (half == 0) {
    uint2 w;
    w.x = (u32)f2b(a0 * inv) | ((u32)f2b(a1 * inv) << 16);
    w.y = (u32)f2b(a2 * inv) | ((u32)f2b(a3 * inv) << 16);
    *(uint2*)(Qb32 + (size_t)node * 64 + hl * 2) = w;
  }
}

// ---------------------------------------------------------------------------
extern "C" void kernel_launch(void* const* d_in, const int* in_sizes, int n_in,
                              void* d_out, int out_size, void* d_ws, size_t ws_size,
                              hipStream_t stream) {
  const float* nf = (const float*)d_in[0];
  const int*   ei = (const int*)  d_in[1];
  const float* ew = (const float*)d_in[2];
  const float* Wq = (const float*)d_in[3];
  const float* bq = (const float*)d_in[4];
  const float* Wk = (const float*)d_in[5];
  const float* bk = (const float*)d_in[6];
  const float* Wv = (const float*)d_in[7];
  const float* bv = (const float*)d_in[8];
  const float* Wo = (const float*)d_in[9];
  const float* bo = (const float*)d_in[10];
  const float* We = (const float*)d_in[11];
  const float* be = (const float*)d_in[12];
  float* out = (float*)d_out;

  char* ws = (char*)d_ws;
  u16*  Wt  = (u16*)ws;                                 // 128 KB
  u16*  Qb  = (u16*)(ws + 131072);                      // 25.6 MB
  u16*  KVi16 = Qb + (size_t)N_NODES * 128;             // 51.2 MB
  char* p   = (char*)(KVi16 + (size_t)N_NODES * 256);
  uint2* stag = (uint2*)p;              p += (size_t)E_EDGES * 8;   // 12.8 MB
  u32*  csr = (u32*)p;                  p += (size_t)E_EDGES * 4;   // 6.4 MB
  int*  off = (int*)p;                  p += (size_t)(N_NODES + 1) * 4;
  u32*  bcnt = (u32*)p;                 p += 512;
  u32*  bbase = (u32*)p;                p += 512;
  u32*  bcur = (u32*)p;                 p += 512;

  const int echunks = (E_EDGES + 4095) / 4096;   // 391

  setup<<<(NBUK + 65536 + 255) / 256, 256, 0, stream>>>(Wq, Wk, Wv, Wo, Wt, bcnt);

  const int mblocks = (N_NODES + 63) / 64;
  gemm_qkv<<<mblocks, 256, 0, stream>>>(nf, Wt, bq, bk, bv, Qb, KVi16, N_NODES);

  bucket_count<<<echunks, 256, 0, stream>>>(ei, bcnt);
  bucket_scan<<<1, 128, 0, stream>>>(bcnt, bbase, bcur);
  pass1_bin<<<echunks, 256, 0, stream>>>(ei, ew, bcur, stag);
  pass2_scatter<<<NBUK, 1024, 0, stream>>>(bbase, stag, off, csr);

  gather_fused<<<(N_NODES + 3) / 4, 256, 0, stream>>>(off, csr,
      (u32*)Qb, (const u32*)KVi16, We, be);

  gemm_out<<<mblocks, 256, 0, stream>>>(Qb, Wt + 49152, bo, out, N_NODES);
}

// Round 8
// 353.793 us; speedup vs baseline: 1.3524x; 1.0678x over previous
//
#include <hip/hip_runtime.h>

#define N_NODES 100000
#define E_EDGES 1600000
// D = HID = 128, H = 4, HD = 32

typedef unsigned short u16;
typedef unsigned int   u32;
typedef float f32x4  __attribute__((ext_vector_type(4)));
typedef short bf16x8 __attribute__((ext_vector_type(8)));

#define NBUK 98            // buckets of 1024 nodes: bucket = tgt >> 10
#define BCAP 20480         // fixed bucket capacity (mean 16384, +32 sigma)

__device__ __forceinline__ u16 f2b(float f) {
  u32 b = __float_as_uint(f);
  return (u16)((b + 0x7FFFu + ((b >> 16) & 1u)) >> 16);
}
__device__ __forceinline__ float blo(u32 u) { return __uint_as_float(u << 16); }
__device__ __forceinline__ float bhi(u32 u) { return __uint_as_float(u & 0xFFFF0000u); }

template<int CTRL>
__device__ __forceinline__ float dpp_add(float d) {
  int x = __builtin_amdgcn_update_dpp(0, __float_as_int(d), CTRL, 0xf, 0xf, true);
  return d + __int_as_float(x);
}
// Reduce across an 8-lane group: xor1, xor2 (quad_perm), then half-row mirror.
__device__ __forceinline__ float reduce8(float d) {
  d = dpp_add<0xB1>(d);    // quad_perm [1,0,3,2]
  d = dpp_add<0x4E>(d);    // quad_perm [2,3,0,1]
  d = dpp_add<0x141>(d);   // row_half_mirror
  return d;
}

// ---------------------------------------------------------------------------
// setup: init bucket cursors to fixed window bases AND transpose+convert W.
// ---------------------------------------------------------------------------
__global__ __launch_bounds__(256) void setup(
    const float* __restrict__ Wq, const float* __restrict__ Wk,
    const float* __restrict__ Wv, const float* __restrict__ Wo,
    u16* __restrict__ Wt, u32* __restrict__ bcur)
{
  int tid = blockIdx.x * 256 + threadIdx.x;
  if (tid < NBUK) bcur[tid] = (u32)tid * BCAP;
  int idx = tid - NBUK;
  if (idx >= 0 && idx < 65536) {
    int mat = idx >> 14;
    int rem = idx & 16383;
    int n = rem >> 7, k = rem & 127;
    const float* W = (mat == 0) ? Wq : (mat == 1) ? Wk : (mat == 2) ? Wv : Wo;
    Wt[idx] = f2b(W[k * 128 + n]);
  }
}

// ---------------------------------------------------------------------------
// Fused QKV: stage A tile once, loop over Wq/Wk/Wv.
// Q -> Qb[node][128] bf16.  K,V -> KVi[node]: elem group g = c>>2 occupies
// u16 slots [8g..8g+7] = {K elems 4g..4g+3, V elems 4g..4g+3}.
// ---------------------------------------------------------------------------
__global__ __launch_bounds__(256) void gemm_qkv(
    const float* __restrict__ A, const u16* __restrict__ Wt,
    const float* __restrict__ bq, const float* __restrict__ bk,
    const float* __restrict__ bv,
    u16* __restrict__ Qb, u16* __restrict__ KVi16, int M)
{
  __shared__ u16 Alds[64][136];
  __shared__ u16 Blds[128][136];
  const int t = threadIdx.x;
  const int row0 = blockIdx.x * 64;

#pragma unroll
  for (int i = 0; i < 8; ++i) {
    int f = t + i * 256;
    int r = f >> 5, c4 = f & 31;
    int gr = row0 + r; if (gr >= M) gr = M - 1;
    float4 v = ((const float4*)(A + (size_t)gr * 128))[c4];
    u16* dst = &Alds[r][c4 * 4];
    dst[0] = f2b(v.x); dst[1] = f2b(v.y); dst[2] = f2b(v.z); dst[3] = f2b(v.w);
  }

  const int lane = t & 63;
  const int mrow = lane & 15;
  const int q    = lane >> 4;
  const int m0   = (t >> 6) * 16;

  for (int m = 0; m < 3; ++m) {
    __syncthreads();
#pragma unroll
    for (int i = 0; i < 8; ++i) {
      int f = t + i * 256;
      int r = f >> 4, c8 = f & 15;
      uint4 v = ((const uint4*)(Wt + (size_t)m * 16384 + (size_t)r * 128))[c8];
      *(uint4*)&Blds[r][c8 * 8] = v;
    }
    __syncthreads();

    f32x4 acc[8];
#pragma unroll
    for (int c = 0; c < 8; ++c) acc[c] = (f32x4){0.f, 0.f, 0.f, 0.f};
#pragma unroll
    for (int kk = 0; kk < 4; ++kk) {
      const int kb = kk * 32 + q * 8;
      bf16x8 a = *(const bf16x8*)&Alds[m0 + mrow][kb];
#pragma unroll
      for (int c = 0; c < 8; ++c) {
        bf16x8 b = *(const bf16x8*)&Blds[c * 16 + mrow][kb];
        acc[c] = __builtin_amdgcn_mfma_f32_16x16x32_bf16(a, b, acc[c], 0, 0, 0);
      }
    }

    const float* bias = (m == 0) ? bq : (m == 1) ? bk : bv;
#pragma unroll
    for (int c = 0; c < 8; ++c) {
      int gcol = c * 16 + mrow;
      float bvv = bias[gcol];
#pragma unroll
      for (int r = 0; r < 4; ++r) {
        int grow = row0 + m0 + q * 4 + r;
        if (grow < M) {
          u16 val = f2b(acc[c][r] + bvv);
          if (m == 0) {
            Qb[(size_t)grow * 128 + gcol] = val;
          } else {
            int slot = ((gcol >> 2) << 3) + ((m == 2) ? 4 : 0) + (gcol & 3);
            KVi16[(size_t)grow * 256 + slot] = val;
          }
        }
      }
    }
  }
}

// ---------------------------------------------------------------------------
// Final: out(Mx128,f32) = A(bf16, Mx128) @ Wo + bo
// ---------------------------------------------------------------------------
__global__ __launch_bounds__(256) void gemm_out(
    const u16* __restrict__ A, const u16* __restrict__ Wt,
    const float* __restrict__ bias, float* __restrict__ Cout, int M)
{
  __shared__ u16 Alds[64][136];
  __shared__ u16 Blds[128][136];
  const int t = threadIdx.x;
  const int row0 = blockIdx.x * 64;

#pragma unroll
  for (int i = 0; i < 4; ++i) {
    int f = t + i * 256;
    int r = f >> 4, c8 = f & 15;
    int gr = row0 + r; if (gr >= M) gr = M - 1;
    uint4 v = ((const uint4*)(A + (size_t)gr * 128))[c8];
    *(uint4*)&Alds[r][c8 * 8] = v;
  }
#pragma unroll
  for (int i = 0; i < 8; ++i) {
    int f = t + i * 256;
    int r = f >> 4, c8 = f & 15;
    uint4 v = ((const uint4*)(Wt + (size_t)r * 128))[c8];
    *(uint4*)&Blds[r][c8 * 8] = v;
  }
  __syncthreads();

  const int lane = t & 63;
  const int mrow = lane & 15;
  const int q    = lane >> 4;
  const int m0   = (t >> 6) * 16;

  f32x4 acc[8];
#pragma unroll
  for (int c = 0; c < 8; ++c) acc[c] = (f32x4){0.f, 0.f, 0.f, 0.f};
#pragma unroll
  for (int kk = 0; kk < 4; ++kk) {
    const int kb = kk * 32 + q * 8;
    bf16x8 a = *(const bf16x8*)&Alds[m0 + mrow][kb];
#pragma unroll
    for (int c = 0; c < 8; ++c) {
      bf16x8 b = *(const bf16x8*)&Blds[c * 16 + mrow][kb];
      acc[c] = __builtin_amdgcn_mfma_f32_16x16x32_bf16(a, b, acc[c], 0, 0, 0);
    }
  }

#pragma unroll
  for (int c = 0; c < 8; ++c) {
    int gcol = c * 16 + mrow;
    float bv = bias[gcol];
#pragma unroll
    for (int r = 0; r < 4; ++r) {
      int grow = row0 + m0 + q * 4 + r;
      if (grow < M) Cout[(size_t)grow * 128 + gcol] = acc[c][r] + bv;
    }
  }
}

// ---------------------------------------------------------------------------
// pass1: bin 4096 edges/block by bucket via LDS counting sort; claim one
// contiguous run per bucket (single atomicAdd on bcur, windows pre-based at
// b*BCAP) and write staged (tgt,payload) pairs in coalesced runs.
// payload = (src<<15) | ew_q15.
// ---------------------------------------------------------------------------
__global__ __launch_bounds__(256) void pass1_bin(
    const int* __restrict__ ei, const float* __restrict__ ew,
    u32* __restrict__ bcur, uint2* __restrict__ stag)
{
  __shared__ u32 s_px[4096];
  __shared__ u32 s_py[4096];
  __shared__ u32 s_gp[4096];
  __shared__ u32 s_hist[NBUK];
  __shared__ u32 s_excl[NBUK];
  __shared__ u32 s_gbase[NBUK];
  __shared__ int s_scan[128];
  const int t = threadIdx.x;
  const int base = blockIdx.x * 4096;
  const int nv = min(4096, E_EDGES - base);

  if (t < NBUK) s_hist[t] = 0;
  __syncthreads();

  u32 tg[16], py[16];
#pragma unroll
  for (int i = 0; i < 16; ++i) {
    int li = t + i * 256;
    bool valid = li < nv;
    int e = base + (valid ? li : 0);
    tg[i] = (u32)ei[E_EDGES + e];
    u32 src = (u32)ei[e];
    u32 ewq = (u32)(ew[e] * 32768.0f);
    py[i] = (src << 15) | ewq;
    if (valid) atomicAdd(&s_hist[tg[i] >> 10], 1u);
    else tg[i] = 0xFFFFFFFFu;
  }
  __syncthreads();

  // scan 98 counts (128-lane ladder; all 256 threads hit the syncs)
  {
    int v = (t < NBUK) ? (int)s_hist[t] : 0;
    if (t < 128) s_scan[t] = v;
    __syncthreads();
    for (int d = 1; d < 128; d <<= 1) {
      int x = (t >= d && t < 128) ? s_scan[t - d] : 0;
      __syncthreads();
      if (t < 128) s_scan[t] += x;
      __syncthreads();
    }
    if (t < NBUK) {
      s_excl[t] = (u32)(s_scan[t] - v);
      s_gbase[t] = (v > 0) ? atomicAdd(&bcur[t], (u32)v) : 0u;
    }
  }
  __syncthreads();
  if (t < NBUK) s_hist[t] = s_excl[t];   // reuse as LDS cursor
  __syncthreads();

#pragma unroll
  for (int i = 0; i < 16; ++i) {
    if (tg[i] != 0xFFFFFFFFu) {
      u32 bk = tg[i] >> 10;
      u32 lp = atomicAdd(&s_hist[bk], 1u);
      s_px[lp] = tg[i];
      s_py[lp] = py[i];
      s_gp[lp] = s_gbase[bk] + (lp - s_excl[bk]);
    }
  }
  __syncthreads();
  for (int s = t; s < nv; s += 256)
    stag[s_gp[s]] = make_uint2(s_px[s], s_py[s]);
}

// ---------------------------------------------------------------------------
// pass2: one block per bucket. LDS per-node histogram + scan -> nodeinfo
// {start,deg}; then scatter staged entries via LDS cursors into the bucket's
// csr window (random writes confined to ~80 KB -> L2-resident).
// ---------------------------------------------------------------------------
__global__ __launch_bounds__(1024) void pass2_scatter(
    const u32* __restrict__ bcur, const uint2* __restrict__ stag,
    int2* __restrict__ nodeinfo, u32* __restrict__ csr)
{
  __shared__ int s_hist[1024];
  __shared__ int s_scan[1024];
  const int t = threadIdx.x;
  const int b = blockIdx.x;
  const int sb = b * BCAP;
  const int cnt = (int)bcur[b] - sb;
  const int node_base = b << 10;

  s_hist[t] = 0;
  __syncthreads();
  for (int i = t; i < cnt; i += 1024)
    atomicAdd(&s_hist[stag[sb + i].x & 1023], 1);
  __syncthreads();

  int v = s_hist[t];
  s_scan[t] = v;
  __syncthreads();
  for (int d = 1; d < 1024; d <<= 1) {
    int x = (t >= d) ? s_scan[t - d] : 0;
    __syncthreads();
    s_scan[t] += x;
    __syncthreads();
  }
  int excl = s_scan[t] - v;
  int node = node_base + t;
  if (node < N_NODES) nodeinfo[node] = make_int2(sb + excl, v);
  __syncthreads();
  s_hist[t] = sb + excl;   // absolute cursor
  __syncthreads();
  for (int i = t; i < cnt; i += 1024) {
    uint2 pr = stag[sb + i];
    int pos = atomicAdd(&s_hist[pr.x & 1023], 1);
    csr[pos] = pr.y;
  }
}

// ---------------------------------------------------------------------------
// Fused per-node gather, 2 edges per wave (lanes 0-31 even edges, 32-63 odd),
// 4-pair unroll -> 8 edges in flight per wave.
// Within a half: 8 lanes/head, lane owns 4 elems; one uint4 = K-quad+V-quad.
// ---------------------------------------------------------------------------
__global__ __launch_bounds__(256) void gather_fused(
    const int2* __restrict__ nodeinfo, const u32* __restrict__ csr,
    u32* __restrict__ Qb32, const u32* __restrict__ KVi,
    const float* __restrict__ We, const float* __restrict__ be)
{
  int node = blockIdx.x * 4 + (threadIdx.x >> 6);
  int l    = threadIdx.x & 63;
  int half = l >> 5;
  int hl   = l & 31;
  int h    = hl >> 3;

  const float scale = 0.17677669529663687f;   // 1/sqrt(32)
  const float eiq   = 1.0f / 32768.0f;
  uint2 qp = *(const uint2*)(Qb32 + (size_t)node * 64 + hl * 2);
  float qa = blo(qp.x) * scale, qb = bhi(qp.x) * scale;
  float qc = blo(qp.y) * scale, qd = bhi(qp.y) * scale;
  float weq = We[h] * eiq, bE = be[h];
  const u32 laneKV = (u32)hl * 16;

  int2 ni = nodeinfo[node];
  int s0 = ni.x, L = ni.y;
  int npair = L >> 1;
  const u32* cp = csr + s0 + half;
  const char* KVc = (const char*)KVi;

  float a0 = 0.f, a1 = 0.f, a2 = 0.f, a3 = 0.f, sum = 0.f;

  int i = 0;
  for (; i + 4 <= npair; i += 4) {
    u32 c0 = cp[2 * i];
    u32 c1 = cp[2 * i + 2];
    u32 c2 = cp[2 * i + 4];
    u32 c3 = cp[2 * i + 6];
    uint4 kv0 = *(const uint4*)(KVc + (((c0 >> 15) << 9) + laneKV));
    uint4 kv1 = *(const uint4*)(KVc + (((c1 >> 15) << 9) + laneKV));
    uint4 kv2 = *(const uint4*)(KVc + (((c2 >> 15) << 9) + laneKV));
    uint4 kv3 = *(const uint4*)(KVc + (((c3 >> 15) << 9) + laneKV));
    float d0 = qa * blo(kv0.x) + qb * bhi(kv0.x) + qc * blo(kv0.y) + qd * bhi(kv0.y);
    float d1 = qa * blo(kv1.x) + qb * bhi(kv1.x) + qc * blo(kv1.y) + qd * bhi(kv1.y);
    float d2 = qa * blo(kv2.x) + qb * bhi(kv2.x) + qc * blo(kv2.y) + qd * bhi(kv2.y);
    float d3 = qa * blo(kv3.x) + qb * bhi(kv3.x) + qc * blo(kv3.y) + qd * bhi(kv3.y);
    d0 = reduce8(d0); d1 = reduce8(d1);
    d2 = reduce8(d2); d3 = reduce8(d3);
    float p0 = __expf(d0 + (float)(c0 & 32767u) * weq + bE);
    float p1 = __expf(d1 + (float)(c1 & 32767u) * weq + bE);
    float p2 = __expf(d2 + (float)(c2 & 32767u) * weq + bE);
    float p3 = __expf(d3 + (float)(c3 & 32767u) * weq + bE);
    sum += (p0 + p1) + (p2 + p3);
    a0 += p0 * blo(kv0.z) + p1 * blo(kv1.z);
    a0 += p2 * blo(kv2.z) + p3 * blo(kv3.z);
    a1 += p0 * bhi(kv0.z) + p1 * bhi(kv1.z);
    a1 += p2 * bhi(kv2.z) + p3 * bhi(kv3.z);
    a2 += p0 * blo(kv0.w) + p1 * blo(kv1.w);
    a2 += p2 * blo(kv2.w) + p3 * blo(kv3.w);
    a3 += p0 * bhi(kv0.w) + p1 * bhi(kv1.w);
    a3 += p2 * bhi(kv2.w) + p3 * bhi(kv3.w);
  }
  for (; i < npair; ++i) {
    u32 c = cp[2 * i];
    uint4 kv = *(const uint4*)(KVc + (((c >> 15) << 9) + laneKV));
    float d = qa * blo(kv.x) + qb * bhi(kv.x) + qc * blo(kv.y) + qd * bhi(kv.y);
    d = reduce8(d);
    float p = __expf(d + (float)(c & 32767u) * weq + bE);
    sum += p;
    a0 += p * blo(kv.z);
    a1 += p * bhi(kv.z);
    a2 += p * blo(kv.w);
    a3 += p * bhi(kv.w);
  }
  if (L & 1) {
    u32 c = csr[s0 + L - 1];
    uint4 kv = *(const uint4*)(KVc + (((c >> 15) << 9) + laneKV));
    float d = qa * blo(kv.x) + qb * bhi(kv.x) + qc * blo(kv.y) + qd * bhi(kv.y);
    d = reduce8(d);
    float p = __expf(d + (float)(c & 32767u) * weq + bE);
    p = half ? 0.f : p;
    sum += p;
    a0 += p * blo(kv.z);
    a1 += p * bhi(kv.z);
    a2 += p * blo(kv.w);
    a3 += p * bhi(kv.w);
  }

  sum += __shfl_xor(sum, 32, 64);
  a0  += __shfl_xor(a0, 32, 64);
  a1  += __shfl_xor(a1, 32, 64);
  a2  += __shfl_xor(a2, 32, 64);
  a3  += __shfl_xor(a3, 32, 64);

  float inv = 1.f / (sum + 1e-8f);
  if (half == 0) {
    uint2 w;
    w.x = (u32)f2b(a0 * inv) | ((u32)f2b(a1 * inv) << 16);
    w.y = (u32)f2b(a2 * inv) | ((u32)f2b(a3 * inv) << 16);
    *(uint2*)(Qb32 + (size_t)node * 64 + hl * 2) = w;
  }
}

// ---------------------------------------------------------------------------
extern "C" void kernel_launch(void* const* d_in, const int* in_sizes, int n_in,
                              void* d_out, int out_size, void* d_ws, size_t ws_size,
                              hipStream_t stream) {
  const float* nf = (const float*)d_in[0];
  const int*   ei = (const int*)  d_in[1];
  const float* ew = (const float*)d_in[2];
  const float* Wq = (const float*)d_in[3];
  const float* bq = (const float*)d_in[4];
  const float* Wk = (const float*)d_in[5];
  const float* bk = (const float*)d_in[6];
  const float* Wv = (const float*)d_in[7];
  const float* bv = (const float*)d_in[8];
  const float* Wo = (const float*)d_in[9];
  const float* bo = (const float*)d_in[10];
  const float* We = (const float*)d_in[11];
  const float* be = (const float*)d_in[12];
  float* out = (float*)d_out;

  char* ws = (char*)d_ws;
  u16*  Wt  = (u16*)ws;                                 // 128 KB
  u16*  Qb  = (u16*)(ws + 131072);                      // 25.6 MB
  u16*  KVi16 = Qb + (size_t)N_NODES * 128;             // 51.2 MB
  char* p   = (char*)(KVi16 + (size_t)N_NODES * 256);
  uint2* stag = (uint2*)p;              p += (size_t)NBUK * BCAP * 8;  // 16.1 MB
  u32*  csr = (u32*)p;                  p += (size_t)NBUK * BCAP * 4;  // 8.0 MB
  int2* nodeinfo = (int2*)p;            p += (size_t)N_NODES * 8;      // 0.8 MB
  u32*  bcur = (u32*)p;                 p += 512;

  const int echunks = (E_EDGES + 4095) / 4096;   // 391

  setup<<<(NBUK + 65536 + 255) / 256, 256, 0, stream>>>(Wq, Wk, Wv, Wo, Wt, bcur);

  const int mblocks = (N_NODES + 63) / 64;
  gemm_qkv<<<mblocks, 256, 0, stream>>>(nf, Wt, bq, bk, bv, Qb, KVi16, N_NODES);

  pass1_bin<<<echunks, 256, 0, stream>>>(ei, ew, bcur, stag);
  pass2_scatter<<<NBUK, 1024, 0, stream>>>(bcur, stag, nodeinfo, csr);

  gather_fused<<<N_NODES / 4, 256, 0, stream>>>(nodeinfo, csr,
      (u32*)Qb, (const u32*)KVi16, We, be);

  gemm_out<<<mblocks, 256, 0, stream>>>(Qb, Wt + 49152, bo, out, N_NODES);
}